// Round 7
// baseline (8399.326 us; speedup 1.0000x reference)
//
#include <hip/hip_runtime.h>
#include <math.h>

// ESN: 512 sequential steps of h = tanh([h | x_t] @ [W_hh|W_ih]^T + b)
// T=512, B=64, I=128, H=1024, K' = 1152.
//
// R11 (from R9 @ 3.11 ms; R10 hung): XCD-local h exchange, hang-proofed.
//  * Remap: bgrp = wg&7, jblk = wg>>3. Under round-robin dispatch (xcd=wg%8)
//    all 32 WGs of a bgrp share one XCD -> h/flag exchange via that XCD's L2
//    (sc0-only, ~200cy) instead of the device coherence point (sc0 sc1,
//    ~700-900cy).
//  * Vote is bgrp-LOCAL (32-wide count over the same WG set the flag
//    protocol already requires co-resident) -- no grid-wide spin.
//  * Hang-proof flags: fast path DUAL-publishes (sc0 store + sc0sc1 store),
//    and polls alternate 15x sc0 / 1x sc0sc1. Progress is guaranteed by the
//    proven sc0sc1 pair even if sc0 load semantics differ from assumed.
//  * Data is sc0-only on the fast path: h-row addresses are fresh every step
//    (never in consumer L1), so stale-L1 reads are impossible; producer's
//    drained sc0 store leaves the line in the shared XCD L2. Cross-XCD
//    mixing is excluded by the consistent per-bgrp vote (G16-safe: slow
//    path = R9's proven coherence-point protocol).
//  * Kept from R9: per-wave k-slice staging in wave-private LDS (no pre-FMA
//    barrier), one __syncthreads/step, parity-dbuf red[], W+bias VGPR-
//    hoisted all 512 steps, wave-lockstep drain then per-wave publish,
//    x prefetch.

#define T_STEPS 512
#define BATCH   64
#define HDIM    1024
#define IDIM    128
#define KDIM    1152
#define NWG     256
#define NB      8

typedef float f32x4_t __attribute__((ext_vector_type(4)));

// flag load: slow ? coherence-point (proven) : XCD-L2 (fast)
__device__ __forceinline__ unsigned flag_load(const unsigned* p, bool slow) {
    unsigned v;
    if (slow)
        asm volatile("global_load_dword %0, %1, off sc0 sc1\n\ts_waitcnt vmcnt(0)"
                     : "=&v"(v) : "v"(p) : "memory");
    else
        asm volatile("global_load_dword %0, %1, off sc0\n\ts_waitcnt vmcnt(0)"
                     : "=&v"(v) : "v"(p) : "memory");
    return v;
}

// 4 x 16B h-row loads from 4 addresses, single drain.
__device__ __forceinline__ void h_load4x4(const float* p0, const float* p1,
                                          const float* p2, const float* p3,
                                          float4& a, float4& b,
                                          float4& c, float4& d, bool byp) {
    if (byp)
        asm volatile(
            "global_load_dwordx4 %0, %4, off sc0 sc1\n\t"
            "global_load_dwordx4 %1, %5, off sc0 sc1\n\t"
            "global_load_dwordx4 %2, %6, off sc0 sc1\n\t"
            "global_load_dwordx4 %3, %7, off sc0 sc1\n\t"
            "s_waitcnt vmcnt(0)"
            : "=&v"(a), "=&v"(b), "=&v"(c), "=&v"(d)
            : "v"(p0), "v"(p1), "v"(p2), "v"(p3)
            : "memory");
    else
        asm volatile(
            "global_load_dwordx4 %0, %4, off sc0\n\t"
            "global_load_dwordx4 %1, %5, off sc0\n\t"
            "global_load_dwordx4 %2, %6, off sc0\n\t"
            "global_load_dwordx4 %3, %7, off sc0\n\t"
            "s_waitcnt vmcnt(0)"
            : "=&v"(a), "=&v"(b), "=&v"(c), "=&v"(d)
            : "v"(p0), "v"(p1), "v"(p2), "v"(p3)
            : "memory");
}

// data store + wave-lockstep drain (s_waitcnt drains all lanes' stores)
__device__ __forceinline__ void out_store4(float* p, float4 v, bool byp) {
    f32x4_t t;
    t.x = v.x; t.y = v.y; t.z = v.z; t.w = v.w;
    if (byp)
        asm volatile("global_store_dwordx4 %0, %1, off sc0 sc1\n\ts_waitcnt vmcnt(0)"
                     :: "v"(p), "v"(t) : "memory");
    else
        asm volatile("global_store_dwordx4 %0, %1, off sc0\n\ts_waitcnt vmcnt(0)"
                     :: "v"(p), "v"(t) : "memory");
}

// flag publish: fast path dual-publishes (local L2 + coherence point) so
// BOTH poll flavors are guaranteed to eventually observe it.
__device__ __forceinline__ void flag_store(unsigned* p, unsigned v, bool byp) {
    if (byp)
        asm volatile("global_store_dword %0, %1, off sc0 sc1"
                     :: "v"(p), "v"(v) : "memory");
    else
        asm volatile("global_store_dword %0, %1, off sc0\n\t"
                     "global_store_dword %0, %1, off sc0 sc1"
                     :: "v"(p), "v"(v) : "memory");
}

// src[R][C] -> dst[C][R], 64x64 LDS tiles, grid = (C/64)*(R/64), 256 thr
__global__ void transpose_f32(const float* __restrict__ src, float* __restrict__ dst,
                              int R, int C) {
    __shared__ float tile[64][65];
    const int tcol = threadIdx.x & 63;
    const int trow = threadIdx.x >> 6;
    const int nbx = C >> 6;
    const int bx = blockIdx.x % nbx;
    const int by = blockIdx.x / nbx;
    const int c0 = bx << 6, r0 = by << 6;
    for (int i = trow; i < 64; i += 4)
        tile[i][tcol] = src[(size_t)(r0 + i) * C + c0 + tcol];
    __syncthreads();
    for (int i = trow; i < 64; i += 4)
        dst[(size_t)(c0 + i) * R + r0 + tcol] = tile[tcol][i];
}

__global__ __launch_bounds__(512) void esn_persistent(
    const float* __restrict__ x,     // [512][64][128]
    const float* __restrict__ h0,    // [64][1024]
    const float* __restrict__ WT,    // [1152][1024]
    const float* __restrict__ bias,  // [1024]
    float* __restrict__ out,         // [512][64][1024]
    float* __restrict__ hfin,        // [64][1024]
    unsigned* flags)                 // [8 bgrp][32 jblk][8 row] + vote
{
    const int tid  = threadIdx.x;
    const int wg   = blockIdx.x;
    const int wave = tid >> 6;                       // 0..7 (k-slice / epi row)
    const int lane = tid & 63;
    const int jq   = lane & 7;                       // 4 j each -> 32 j
    const int ksub = lane >> 3;                      // 0..7 k-interleave
    const int bgrp = wg & 7;                         // = XCD under round-robin
    const int jblk = wg >> 3;                        // 0..31
    const int b0   = bgrp << 3;
    const int j0   = (jblk << 5) + (jq << 2);
    const int krec = wave << 7;                      // recurrent k base (128/wave)
    const int kx   = HDIM + (wave << 4) + (ksub << 1);  // x-part rows (2 each)

    // wave-private staging blocks
    __shared__ float  ht2[8 * 1024];                 // [wave][8 rows][128 k] 32KB
    __shared__ float  htx[8 * 128];                  // [wave][8 rows][16 xk]  4KB
    __shared__ float4 red[2][8 * 8 * 9];             // parity-dbuf reduce    18KB
    __shared__ int    fast_sh;

    // ---- one-time bgrp-local vote: all 32 WGs of this bgrp on one XCD? ----
    unsigned* vmask = flags + 2048;                  // [8]
    unsigned* vcnt  = flags + 2056;                  // [8]
    if (tid == 0) {
        unsigned xcd;
        asm volatile("s_getreg_b32 %0, hwreg(HW_REG_XCC_ID)" : "=s"(xcd));
        __hip_atomic_fetch_or(&vmask[bgrp], 1u << (xcd & 7), __ATOMIC_RELAXED,
                              __HIP_MEMORY_SCOPE_AGENT);
        __hip_atomic_fetch_add(&vcnt[bgrp], 1u, __ATOMIC_RELEASE,
                               __HIP_MEMORY_SCOPE_AGENT);
        while (__hip_atomic_load(&vcnt[bgrp], __ATOMIC_ACQUIRE,
                                 __HIP_MEMORY_SCOPE_AGENT) < 32u) {}
        unsigned m = __hip_atomic_load(&vmask[bgrp], __ATOMIC_RELAXED,
                                       __HIP_MEMORY_SCOPE_AGENT);
        fast_sh = (__popc(m) == 1);
    }
    __syncthreads();
    const bool byp = (fast_sh == 0);   // true -> coherence-point (slow, proven)

    // ---- hoist all 18 W float4 loads for ALL 512 steps (72 VGPRs) ----
    float4 Wv[18];
    {
        const float* wp = WT + (size_t)krec * HDIM + j0;
        #pragma unroll
        for (int i = 0; i < 4; ++i) {
            const int kk = ((i << 3) + ksub) << 2;      // 0..124 step 4
            const float* wk = wp + (size_t)kk * HDIM;
            Wv[i * 4 + 0] = *(const float4*)(wk);
            Wv[i * 4 + 1] = *(const float4*)(wk + HDIM);
            Wv[i * 4 + 2] = *(const float4*)(wk + 2 * HDIM);
            Wv[i * 4 + 3] = *(const float4*)(wk + 3 * HDIM);
        }
        const float* wkx = WT + (size_t)kx * HDIM + j0;
        Wv[16] = *(const float4*)(wkx);
        Wv[17] = *(const float4*)(wkx + HDIM);
    }

    // ---- epilogue constants: lanes 0-7 of wave v handle row b0+v ----
    float4 b4 = make_float4(0.f, 0.f, 0.f, 0.f);
    int jj = 0;
    if (lane < 8) {
        jj = (jblk << 5) + (lane << 2);
        b4 = *(const float4*)(bias + jj);
    }

    // ---- flag layout: fl[(bgrp<<8) + (jblk<<3) + row] ----
    unsigned* fl_pub = flags + (bgrp << 8) + (jblk << 3) + wave;
    const unsigned* fl_poll = flags + (bgrp << 8) + (wave << 5) + (lane & 31);

    // ---- staging lane maps ----
    const int sbb = lane >> 5;                 // row parity (0/1)
    const int sko = (lane & 31) << 2;          // k-offset within slice
    float* hdst = ht2 + (wave << 10) + (lane << 2);      // contiguous 1KB/instr
    const int xr = lane >> 3;                  // x row
    const int xco = (lane & 7) << 1;           // x col-offset within slice
    float* xdst = htx + (wave << 7) + (xr << 4) + xco;
    const float* hb = ht2 + (wave << 10);
    const float* xb = htx + (wave << 7);

    // ---- prefetch x slice for t=0 (plain cached load, x read-only) ----
    float2 xv2 = *(const float2*)(x + (size_t)(b0 + xr) * IDIM + (wave << 4) + xco);

    for (int t = 0; t < T_STEPS; ++t) {
        // ---- stage this wave's k-slice of 8 rows into wave-private LDS ----
        *(float2*)xdst = xv2;
        if (t == 0) {
            const float* p = h0 + (size_t)(b0 + sbb) * HDIM + krec + sko;
            *(float4*)(hdst)       = *(const float4*)(p);
            *(float4*)(hdst + 256) = *(const float4*)(p + 2 * HDIM);
            *(float4*)(hdst + 512) = *(const float4*)(p + 4 * HDIM);
            *(float4*)(hdst + 768) = *(const float4*)(p + 6 * HDIM);
        } else {
            // wait for THIS wave's 32 producers (4 jblk x 8 rows, coalesced).
            // Alternate 15x fast / 1x proven poll: progress guaranteed.
            unsigned n = 0, f;
            do {
                ++n;
                f = flag_load(fl_poll, byp || ((n & 15u) == 0u));
            } while (!__all((int)(f >= (unsigned)t)));
            const float* p = out + ((size_t)(t - 1) * BATCH + b0 + sbb) * HDIM
                             + krec + sko;
            float4 a, b, c, d;
            h_load4x4(p, p + 2 * HDIM, p + 4 * HDIM, p + 6 * HDIM,
                      a, b, c, d, byp);
            *(float4*)(hdst)       = a;
            *(float4*)(hdst + 256) = b;
            *(float4*)(hdst + 512) = c;
            *(float4*)(hdst + 768) = d;
        }
        // NO __syncthreads: staged data is wave-private.

        // prefetch next x slice; latency hides under the FMA phase
        if (t + 1 < T_STEPS)
            xv2 = *(const float2*)(x + ((size_t)(t + 1) * BATCH + b0 + xr) * IDIM
                                   + (wave << 4) + xco);

        // ---- FMA: acc[b] over this thread's k (W in registers) ----
        float4 acc[NB];
        #pragma unroll
        for (int bb = 0; bb < NB; ++bb) acc[bb] = make_float4(0.f, 0.f, 0.f, 0.f);

        #pragma unroll
        for (int i = 0; i < 4; ++i) {
            const int ko = ((i << 3) + ksub) << 2;       // 0..124 step 4
            const float4 w0 = Wv[i * 4 + 0], w1 = Wv[i * 4 + 1];
            const float4 w2 = Wv[i * 4 + 2], w3 = Wv[i * 4 + 3];
            #pragma unroll
            for (int bb = 0; bb < NB; ++bb) {
                float4 h4 = *(const float4*)(hb + (bb << 7) + ko);
                acc[bb].x = fmaf(w0.x, h4.x, acc[bb].x);
                acc[bb].y = fmaf(w0.y, h4.x, acc[bb].y);
                acc[bb].z = fmaf(w0.z, h4.x, acc[bb].z);
                acc[bb].w = fmaf(w0.w, h4.x, acc[bb].w);
                acc[bb].x = fmaf(w1.x, h4.y, acc[bb].x);
                acc[bb].y = fmaf(w1.y, h4.y, acc[bb].y);
                acc[bb].z = fmaf(w1.z, h4.y, acc[bb].z);
                acc[bb].w = fmaf(w1.w, h4.y, acc[bb].w);
                acc[bb].x = fmaf(w2.x, h4.z, acc[bb].x);
                acc[bb].y = fmaf(w2.y, h4.z, acc[bb].y);
                acc[bb].z = fmaf(w2.z, h4.z, acc[bb].z);
                acc[bb].w = fmaf(w2.w, h4.z, acc[bb].w);
                acc[bb].x = fmaf(w3.x, h4.w, acc[bb].x);
                acc[bb].y = fmaf(w3.y, h4.w, acc[bb].y);
                acc[bb].z = fmaf(w3.z, h4.w, acc[bb].z);
                acc[bb].w = fmaf(w3.w, h4.w, acc[bb].w);
            }
        }
        // x tail: 2 k per thread
        #pragma unroll
        for (int bb = 0; bb < NB; ++bb) {
            float2 hx = *(const float2*)(xb + (bb << 4) + (ksub << 1));
            acc[bb].x = fmaf(Wv[16].x, hx.x, acc[bb].x);
            acc[bb].y = fmaf(Wv[16].y, hx.x, acc[bb].y);
            acc[bb].z = fmaf(Wv[16].z, hx.x, acc[bb].z);
            acc[bb].w = fmaf(Wv[16].w, hx.x, acc[bb].w);
            acc[bb].x = fmaf(Wv[17].x, hx.y, acc[bb].x);
            acc[bb].y = fmaf(Wv[17].y, hx.y, acc[bb].y);
            acc[bb].z = fmaf(Wv[17].z, hx.y, acc[bb].z);
            acc[bb].w = fmaf(Wv[17].w, hx.y, acc[bb].w);
        }

        // ---- reduce over ksub (lane bits 3,4,5) ----
        #pragma unroll
        for (int bb = 0; bb < NB; ++bb) {
            acc[bb].x += __shfl_xor(acc[bb].x, 8);
            acc[bb].y += __shfl_xor(acc[bb].y, 8);
            acc[bb].z += __shfl_xor(acc[bb].z, 8);
            acc[bb].w += __shfl_xor(acc[bb].w, 8);
            acc[bb].x += __shfl_xor(acc[bb].x, 16);
            acc[bb].y += __shfl_xor(acc[bb].y, 16);
            acc[bb].z += __shfl_xor(acc[bb].z, 16);
            acc[bb].w += __shfl_xor(acc[bb].w, 16);
            acc[bb].x += __shfl_xor(acc[bb].x, 32);
            acc[bb].y += __shfl_xor(acc[bb].y, 32);
            acc[bb].z += __shfl_xor(acc[bb].z, 32);
            acc[bb].w += __shfl_xor(acc[bb].w, 32);
        }
        if (ksub == 0) {
            #pragma unroll
            for (int bb = 0; bb < NB; ++bb)
                red[t & 1][((wave << 3) + jq) * 9 + bb] = acc[bb];
        }
        __syncthreads();                               // red[t&1] complete

        // ---- per-wave epilogue for row b0+wave: lanes 0-7 ----
        if (lane < 8) {
            float4 s = make_float4(0.f, 0.f, 0.f, 0.f);
            #pragma unroll
            for (int w = 0; w < 8; ++w) {
                float4 r = red[t & 1][((w << 3) + lane) * 9 + wave];
                s.x += r.x; s.y += r.y; s.z += r.z; s.w += r.w;
            }
            float4 o;
            o.x = tanhf(s.x + b4.x);
            o.y = tanhf(s.y + b4.y);
            o.z = tanhf(s.z + b4.z);
            o.w = tanhf(s.w + b4.w);
            // store + wave-lockstep drain, then publish
            out_store4(out + ((size_t)t * BATCH + b0 + wave) * HDIM + jj, o, byp);
            if (t == T_STEPS - 1)
                *(float4*)(hfin + (size_t)(b0 + wave) * HDIM + jj) = o;
        }
        if (lane == 0)
            flag_store(fl_pub, (unsigned)(t + 1), byp);
    }
}

extern "C" void kernel_launch(void* const* d_in, const int* in_sizes, int n_in,
                              void* d_out, int out_size, void* d_ws, size_t ws_size,
                              hipStream_t stream) {
    const float* x    = (const float*)d_in[0];
    const float* h0   = (const float*)d_in[1];
    const float* w_ih = (const float*)d_in[2];   // [1024][128]
    const float* w_hh = (const float*)d_in[3];   // [1024][1024]
    const float* bias = (const float*)d_in[4];   // [1024]
    float* out = (float*)d_out;

    char* ws = (char*)d_ws;
    float*    WT    = (float*)ws;                // [1152][1024] = 4.72 MB
    unsigned* flags = (unsigned*)(ws + 4718592); // 2048 flag dwords + vote

    (void)hipMemsetAsync(flags, 0, 8192 + 128, stream);
    transpose_f32<<<256, 256, 0, stream>>>(w_hh, WT, HDIM, HDIM);
    transpose_f32<<<32, 256, 0, stream>>>(w_ih, WT + (size_t)HDIM * HDIM, HDIM, IDIM);
    esn_persistent<<<NWG, 512, 0, stream>>>(x, h0, WT, bias,
                                            out, out + (size_t)T_STEPS * BATCH * HDIM,
                                            flags);
}

// Round 8
// 2766.752 us; speedup vs baseline: 3.0358x; 3.0358x over previous
//
#include <hip/hip_runtime.h>
#include <math.h>

// ESN: 512 sequential steps of h = tanh([h | x_t] @ [W_hh|W_ih]^T + b)
// T=512, B=64, I=128, H=1024, K' = 1152.
//
// R12 (from R9 @ 3.11 ms; R11's sc0-only XCD-local exchange was 2.7x SLOWER
// -- only sc0+sc1 coherence-point visibility is proven prompt on gfx950):
// FLAGLESS sentinel sync -- poll the data itself.
//  * out[] is pre-poisoned with byte 0x7F (dword 0x7F7F7F7F = 3.4e38,
//    unreachable by tanh). Consumers load their h-chunk (sc0 sc1) and retry
//    while any dword is still poison. Validity is fused into the data:
//    the per-step critical path is ONE one-way store + ONE poll RT, instead
//    of R9's drain-RT + flag-flight + flag-observe-RT + data-RT.
//  * Each out location is written exactly once per launch -> any non-poison
//    dword is final (partial visibility safe, per-dword monotone).
//  * Producers fire write-through sc0sc1 stores and move on: no vmcnt
//    drain, no flag store. Poison memset is stream-ordered per launch
//    (~25us for 128 MB), so replays re-arm correctly.
//  * Kept from R9 (proven): bgrp=wg>>5 / XCD-swizzled jblk mapping,
//    per-wave k-slice staging into wave-private LDS (no pre-FMA barrier),
//    one __syncthreads/step, parity-dbuf red[], W (18 float4) + bias
//    VGPR-resident all 512 steps, x prefetch.

#define T_STEPS 512
#define BATCH   64
#define HDIM    1024
#define IDIM    128
#define KDIM    1152
#define NWG     256
#define NB      8
#define POISON  0x7F7F7F7Fu

typedef float f32x4_t __attribute__((ext_vector_type(4)));

// 4 x 16B coherence-point loads from 4 addresses, single drain.
__device__ __forceinline__ void sc_load4x4(const float* p0, const float* p1,
                                           const float* p2, const float* p3,
                                           float4& a, float4& b,
                                           float4& c, float4& d) {
    asm volatile(
        "global_load_dwordx4 %0, %4, off sc0 sc1\n\t"
        "global_load_dwordx4 %1, %5, off sc0 sc1\n\t"
        "global_load_dwordx4 %2, %6, off sc0 sc1\n\t"
        "global_load_dwordx4 %3, %7, off sc0 sc1\n\t"
        "s_waitcnt vmcnt(0)"
        : "=&v"(a), "=&v"(b), "=&v"(c), "=&v"(d)
        : "v"(p0), "v"(p1), "v"(p2), "v"(p3)
        : "memory");
}

// write-through store (no drain: visibility rides the write, consumers
// poll the data; the compiler's own waitcnt handles VGPR reuse)
__device__ __forceinline__ void sc_store4_nodrain(float* p, float4 v) {
    f32x4_t t;
    t.x = v.x; t.y = v.y; t.z = v.z; t.w = v.w;
    asm volatile("global_store_dwordx4 %0, %1, off sc0 sc1"
                 :: "v"(p), "v"(t) : "memory");
}

__device__ __forceinline__ unsigned chk4(float4 v) {
    return (unsigned)((__float_as_uint(v.x) == POISON) |
                      (__float_as_uint(v.y) == POISON) |
                      (__float_as_uint(v.z) == POISON) |
                      (__float_as_uint(v.w) == POISON));
}

// src[R][C] -> dst[C][R], 64x64 LDS tiles, grid = (C/64)*(R/64), 256 thr
__global__ void transpose_f32(const float* __restrict__ src, float* __restrict__ dst,
                              int R, int C) {
    __shared__ float tile[64][65];
    const int tcol = threadIdx.x & 63;
    const int trow = threadIdx.x >> 6;
    const int nbx = C >> 6;
    const int bx = blockIdx.x % nbx;
    const int by = blockIdx.x / nbx;
    const int c0 = bx << 6, r0 = by << 6;
    for (int i = trow; i < 64; i += 4)
        tile[i][tcol] = src[(size_t)(r0 + i) * C + c0 + tcol];
    __syncthreads();
    for (int i = trow; i < 64; i += 4)
        dst[(size_t)(c0 + i) * R + r0 + tcol] = tile[tcol][i];
}

__global__ __launch_bounds__(512) void esn_persistent(
    const float* __restrict__ x,     // [512][64][128]
    const float* __restrict__ h0,    // [64][1024]
    const float* __restrict__ WT,    // [1152][1024]
    const float* __restrict__ bias,  // [1024]
    float* __restrict__ out,         // [512][64][1024] (pre-poisoned)
    float* __restrict__ hfin)        // [64][1024]
{
    const int tid  = threadIdx.x;
    const int wg   = blockIdx.x;
    const int wave = tid >> 6;                       // 0..7 (k-slice / epi row)
    const int lane = tid & 63;
    const int jq   = lane & 7;                       // 4 j each -> 32 j
    const int ksub = lane >> 3;                      // 0..7 k-interleave
    const int jblk = ((wg & 7) << 2) | ((wg >> 3) & 3);  // XCD owns 4 jblks
    const int bgrp = wg >> 5;                            // 0..7
    const int b0   = bgrp << 3;
    const int j0   = (jblk << 5) + (jq << 2);
    const int krec = wave << 7;                      // recurrent k base (128/wave)
    const int kx   = HDIM + (wave << 4) + (ksub << 1);  // x-part rows (2 each)

    // wave-private staging blocks
    __shared__ float  ht2[8 * 1024];                 // [wave][8 rows][128 k] 32KB
    __shared__ float  htx[8 * 128];                  // [wave][8 rows][16 xk]  4KB
    __shared__ float4 red[2][8 * 8 * 9];             // parity-dbuf reduce    18KB

    // ---- hoist all 18 W float4 loads for ALL 512 steps (72 VGPRs) ----
    float4 Wv[18];
    {
        const float* wp = WT + (size_t)krec * HDIM + j0;
        #pragma unroll
        for (int i = 0; i < 4; ++i) {
            const int kk = ((i << 3) + ksub) << 2;      // 0..124 step 4
            const float* wk = wp + (size_t)kk * HDIM;
            Wv[i * 4 + 0] = *(const float4*)(wk);
            Wv[i * 4 + 1] = *(const float4*)(wk + HDIM);
            Wv[i * 4 + 2] = *(const float4*)(wk + 2 * HDIM);
            Wv[i * 4 + 3] = *(const float4*)(wk + 3 * HDIM);
        }
        const float* wkx = WT + (size_t)kx * HDIM + j0;
        Wv[16] = *(const float4*)(wkx);
        Wv[17] = *(const float4*)(wkx + HDIM);
    }

    // ---- epilogue constants: lanes 0-7 of wave v handle row b0+v ----
    float4 b4 = make_float4(0.f, 0.f, 0.f, 0.f);
    int jj = 0;
    if (lane < 8) {
        jj = (jblk << 5) + (lane << 2);
        b4 = *(const float4*)(bias + jj);
    }

    // ---- staging lane maps ----
    const int sbb = lane >> 5;                 // row parity (0/1)
    const int sko = (lane & 31) << 2;          // k-offset within slice
    float* hdst = ht2 + (wave << 10) + (lane << 2);      // contiguous 1KB/instr
    const int xr = lane >> 3;                  // x row
    const int xco = (lane & 7) << 1;           // x col-offset within slice
    float* xdst = htx + (wave << 7) + (xr << 4) + xco;
    const float* hb = ht2 + (wave << 10);
    const float* xb = htx + (wave << 7);

    // ---- prefetch x slice for t=0 (plain cached load, x read-only) ----
    float2 xv2 = *(const float2*)(x + (size_t)(b0 + xr) * IDIM + (wave << 4) + xco);

    for (int t = 0; t < T_STEPS; ++t) {
        // ---- stage this wave's k-slice of 8 rows into wave-private LDS ----
        *(float2*)xdst = xv2;
        if (t == 0) {
            const float* p = h0 + (size_t)(b0 + sbb) * HDIM + krec + sko;
            *(float4*)(hdst)       = *(const float4*)(p);
            *(float4*)(hdst + 256) = *(const float4*)(p + 2 * HDIM);
            *(float4*)(hdst + 512) = *(const float4*)(p + 4 * HDIM);
            *(float4*)(hdst + 768) = *(const float4*)(p + 6 * HDIM);
        } else {
            // sentinel poll: data IS the flag. Retry until no dword is
            // poison; each location is written once, so non-poison = final.
            const float* p = out + ((size_t)(t - 1) * BATCH + b0 + sbb) * HDIM
                             + krec + sko;
            float4 a, b, c, d;
            do {
                sc_load4x4(p, p + 2 * HDIM, p + 4 * HDIM, p + 6 * HDIM,
                           a, b, c, d);
            } while (__any((int)(chk4(a) | chk4(b) | chk4(c) | chk4(d))));
            *(float4*)(hdst)       = a;
            *(float4*)(hdst + 256) = b;
            *(float4*)(hdst + 512) = c;
            *(float4*)(hdst + 768) = d;
        }
        // NO __syncthreads: staged data is wave-private.

        // prefetch next x slice; latency hides under the FMA phase
        if (t + 1 < T_STEPS)
            xv2 = *(const float2*)(x + ((size_t)(t + 1) * BATCH + b0 + xr) * IDIM
                                   + (wave << 4) + xco);

        // ---- FMA: acc[b] over this thread's k (W in registers) ----
        float4 acc[NB];
        #pragma unroll
        for (int bb = 0; bb < NB; ++bb) acc[bb] = make_float4(0.f, 0.f, 0.f, 0.f);

        #pragma unroll
        for (int i = 0; i < 4; ++i) {
            const int ko = ((i << 3) + ksub) << 2;       // 0..124 step 4
            const float4 w0 = Wv[i * 4 + 0], w1 = Wv[i * 4 + 1];
            const float4 w2 = Wv[i * 4 + 2], w3 = Wv[i * 4 + 3];
            #pragma unroll
            for (int bb = 0; bb < NB; ++bb) {
                float4 h4 = *(const float4*)(hb + (bb << 7) + ko);
                acc[bb].x = fmaf(w0.x, h4.x, acc[bb].x);
                acc[bb].y = fmaf(w0.y, h4.x, acc[bb].y);
                acc[bb].z = fmaf(w0.z, h4.x, acc[bb].z);
                acc[bb].w = fmaf(w0.w, h4.x, acc[bb].w);
                acc[bb].x = fmaf(w1.x, h4.y, acc[bb].x);
                acc[bb].y = fmaf(w1.y, h4.y, acc[bb].y);
                acc[bb].z = fmaf(w1.z, h4.y, acc[bb].z);
                acc[bb].w = fmaf(w1.w, h4.y, acc[bb].w);
                acc[bb].x = fmaf(w2.x, h4.z, acc[bb].x);
                acc[bb].y = fmaf(w2.y, h4.z, acc[bb].y);
                acc[bb].z = fmaf(w2.z, h4.z, acc[bb].z);
                acc[bb].w = fmaf(w2.w, h4.z, acc[bb].w);
                acc[bb].x = fmaf(w3.x, h4.w, acc[bb].x);
                acc[bb].y = fmaf(w3.y, h4.w, acc[bb].y);
                acc[bb].z = fmaf(w3.z, h4.w, acc[bb].z);
                acc[bb].w = fmaf(w3.w, h4.w, acc[bb].w);
            }
        }
        // x tail: 2 k per thread
        #pragma unroll
        for (int bb = 0; bb < NB; ++bb) {
            float2 hx = *(const float2*)(xb + (bb << 4) + (ksub << 1));
            acc[bb].x = fmaf(Wv[16].x, hx.x, acc[bb].x);
            acc[bb].y = fmaf(Wv[16].y, hx.x, acc[bb].y);
            acc[bb].z = fmaf(Wv[16].z, hx.x, acc[bb].z);
            acc[bb].w = fmaf(Wv[16].w, hx.x, acc[bb].w);
            acc[bb].x = fmaf(Wv[17].x, hx.y, acc[bb].x);
            acc[bb].y = fmaf(Wv[17].y, hx.y, acc[bb].y);
            acc[bb].z = fmaf(Wv[17].z, hx.y, acc[bb].z);
            acc[bb].w = fmaf(Wv[17].w, hx.y, acc[bb].w);
        }

        // ---- reduce over ksub (lane bits 3,4,5) ----
        #pragma unroll
        for (int bb = 0; bb < NB; ++bb) {
            acc[bb].x += __shfl_xor(acc[bb].x, 8);
            acc[bb].y += __shfl_xor(acc[bb].y, 8);
            acc[bb].z += __shfl_xor(acc[bb].z, 8);
            acc[bb].w += __shfl_xor(acc[bb].w, 8);
            acc[bb].x += __shfl_xor(acc[bb].x, 16);
            acc[bb].y += __shfl_xor(acc[bb].y, 16);
            acc[bb].z += __shfl_xor(acc[bb].z, 16);
            acc[bb].w += __shfl_xor(acc[bb].w, 16);
            acc[bb].x += __shfl_xor(acc[bb].x, 32);
            acc[bb].y += __shfl_xor(acc[bb].y, 32);
            acc[bb].z += __shfl_xor(acc[bb].z, 32);
            acc[bb].w += __shfl_xor(acc[bb].w, 32);
        }
        if (ksub == 0) {
            #pragma unroll
            for (int bb = 0; bb < NB; ++bb)
                red[t & 1][((wave << 3) + jq) * 9 + bb] = acc[bb];
        }
        __syncthreads();                               // red[t&1] complete

        // ---- per-wave epilogue for row b0+wave: lanes 0-7 ----
        if (lane < 8) {
            float4 s = make_float4(0.f, 0.f, 0.f, 0.f);
            #pragma unroll
            for (int w = 0; w < 8; ++w) {
                float4 r = red[t & 1][((w << 3) + lane) * 9 + wave];
                s.x += r.x; s.y += r.y; s.z += r.z; s.w += r.w;
            }
            float4 o;
            o.x = tanhf(s.x + b4.x);
            o.y = tanhf(s.y + b4.y);
            o.z = tanhf(s.z + b4.z);
            o.w = tanhf(s.w + b4.w);
            // fire-and-forget write-through: the store itself is the signal
            sc_store4_nodrain(out + ((size_t)t * BATCH + b0 + wave) * HDIM + jj, o);
            if (t == T_STEPS - 1)
                *(float4*)(hfin + (size_t)(b0 + wave) * HDIM + jj) = o;
        }
    }
}

extern "C" void kernel_launch(void* const* d_in, const int* in_sizes, int n_in,
                              void* d_out, int out_size, void* d_ws, size_t ws_size,
                              hipStream_t stream) {
    const float* x    = (const float*)d_in[0];
    const float* h0   = (const float*)d_in[1];
    const float* w_ih = (const float*)d_in[2];   // [1024][128]
    const float* w_hh = (const float*)d_in[3];   // [1024][1024]
    const float* bias = (const float*)d_in[4];   // [1024]
    float* out = (float*)d_out;

    char* ws = (char*)d_ws;
    float* WT = (float*)ws;                      // [1152][1024] = 4.72 MB

    // poison the polled region (steps 0..T-1): byte 0x7F -> dword 0x7F7F7F7F
    // = 3.4e38, unreachable by tanh. Stream-ordered before the ESN kernel;
    // re-arms on every replay.
    (void)hipMemsetAsync(out, 0x7F,
                         (size_t)T_STEPS * BATCH * HDIM * sizeof(float), stream);
    transpose_f32<<<256, 256, 0, stream>>>(w_hh, WT, HDIM, HDIM);
    transpose_f32<<<32, 256, 0, stream>>>(w_ih, WT + (size_t)HDIM * HDIM, HDIM, IDIM);
    esn_persistent<<<NWG, 512, 0, stream>>>(x, h0, WT, bias,
                                            out, out + (size_t)T_STEPS * BATCH * HDIM);
}